// Round 11
// baseline (293.675 us; speedup 1.0000x reference)
//
#include <hip/hip_runtime.h>
#include <stdint.h>

// MultiHeadAttention: B=2, S=2048, HIDDEN=1024, NH=16, HD=64, causal.
// R11: BARRIER-FREE attention. R10 pipe accounting: LDS pipe ~65% busy (K/V
//      frag reads duplicated 4x across waves + scalar P writes) while VMEM
//      idle (4.5% HBM). K/V frags now load DIRECTLY from global (16-line
//      coalesced per instr, L1/L2-hot tiles); LDS holds only the per-wave P
//      region; zero __syncthreads -> 16 independent waves/CU hide all
//      latency via TLP. launch_bounds(256,4), LDS 8.7 KB.
//      GEMMs/cvt unchanged from R10.
// MFMA 16x16x32 bf16 layouts (HW-verified):
//   A/B frag: lane holds row[m=lane&15][k=(lane>>4)*8 + j]
//   C/D:      row=(lane>>4)*4+reg, col=lane&15

#define HIDDEN 1024
#define NH 16
#define HD 64
#define BATCH 2
#define SEQ 2048

typedef unsigned short u16;
typedef unsigned int u32;
typedef __attribute__((ext_vector_type(8))) short short8;   // 8 bf16
typedef __attribute__((ext_vector_type(4))) float f32x4;

typedef const __attribute__((address_space(1))) u32 gu32;
typedef __attribute__((address_space(3))) u32 lu32;

__device__ __forceinline__ u16 f2bf(float f) {
    u32 u = __float_as_uint(f);
    return (u16)((u + 0x7FFFu + ((u >> 16) & 1u)) >> 16);   // RNE
}

// ---------------- fused fp32 -> bf16 conversion (x + 4 weights) -----------
__global__ void cvt_all(const float* __restrict__ x, const float* __restrict__ Wq,
                        const float* __restrict__ Wk, const float* __restrict__ Wv,
                        const float* __restrict__ Wo, u16* __restrict__ xb,
                        u16* __restrict__ wqb, u16* __restrict__ wkb,
                        u16* __restrict__ wvb, u16* __restrict__ wob) {
    const int blk = blockIdx.x;
    const float* src; u16* dst; int base;
    if (blk < 2048)      { src = x;  dst = xb;  base = blk; }
    else if (blk < 2560) { src = Wq; dst = wqb; base = blk - 2048; }
    else if (blk < 3072) { src = Wk; dst = wkb; base = blk - 2560; }
    else if (blk < 3584) { src = Wv; dst = wvb; base = blk - 3072; }
    else                 { src = Wo; dst = wob; base = blk - 3584; }
    const int i = base * 256 + threadIdx.x;
    float4 a = ((const float4*)src)[2 * i];
    float4 b = ((const float4*)src)[2 * i + 1];
    union { u16 h[8]; uint4 v; } o;
    o.h[0] = f2bf(a.x); o.h[1] = f2bf(a.y); o.h[2] = f2bf(a.z); o.h[3] = f2bf(a.w);
    o.h[4] = f2bf(b.x); o.h[5] = f2bf(b.y); o.h[6] = f2bf(b.z); o.h[7] = f2bf(b.w);
    ((uint4*)dst)[i] = o.v;
}

// ---- async stage: 16 rows x 32 cols (64 B/row) per call, XOR-4 swizzle ----
__device__ __forceinline__ void stage16(const u16* __restrict__ G, int grow0,
                                        int k0, u16* lds, int rbase, int lane) {
    const int sr = lane >> 2;
    const int lc = (lane & 3) ^ (sr & 3);
    const u16* g = G + (size_t)(grow0 + rbase + sr) * 1024 + k0 + lc * 8;
    __builtin_amdgcn_global_load_lds((gu32*)g, (lu32*)(lds + rbase * 32), 16, 0, 0);
}

// ---------------- fused QKV projection (R10, unchanged) -------------------
__launch_bounds__(256, 3)
__global__ void gemm_qkv(const u16* __restrict__ A, const u16* __restrict__ Wqb,
                         const u16* __restrict__ Wkb, const u16* __restrict__ Wvb,
                         const float* __restrict__ bq, const float* __restrict__ bk,
                         const float* __restrict__ bv, u16* __restrict__ Qo,
                         u16* __restrict__ Ko, u16* __restrict__ Vo) {
    __shared__ u16 As[2][128 * 32];   // 2 x 8 KB
    __shared__ u16 Bs[2][128 * 32];   // 2 x 8 KB -> 32 KB total
    const int which = blockIdx.x >> 3;
    const int n0 = (blockIdx.x & 7) * 128;
    const int m0 = blockIdx.y * 128;
    const u16* Wt = (which == 0) ? Wqb : (which == 1) ? Wkb : Wvb;
    const float* bias = (which == 0) ? bq : (which == 1) ? bk : bv;
    u16* out = (which == 0) ? Qo : (which == 1) ? Ko : Vo;
    const float oscale = (which == 0) ? 0.18033688011112042f : 1.0f;  // log2e/8
    const int t = threadIdx.x;
    const int lane = t & 63, w = t >> 6, quad = lane >> 4, lm = lane & 15;
    const int wm = (w & 1) * 64, wn = (w >> 1) * 64;

    f32x4 acc[4][4] = {};

    auto stage = [&](int k0, int buf) {
        stage16(A, m0, k0, As[buf], w * 32, lane);
        stage16(A, m0, k0, As[buf], w * 32 + 16, lane);
        stage16(Wt, n0, k0, Bs[buf], w * 32, lane);
        stage16(Wt, n0, k0, Bs[buf], w * 32 + 16, lane);
    };

    stage(0, 0);
    __syncthreads();
    for (int k0 = 0; k0 < 1024; k0 += 32) {
        const int cur = (k0 >> 5) & 1;
        if (k0 + 32 < 1024) stage(k0 + 32, cur ^ 1);
        short8 af[4], bf[4];
        const int sw = (quad ^ (lm & 3)) * 8;   // swizzled slot offset (elems)
#pragma unroll
        for (int mi = 0; mi < 4; mi++)
            af[mi] = *(const short8*)(&As[cur][(wm + mi * 16 + lm) * 32] + sw);
#pragma unroll
        for (int ni = 0; ni < 4; ni++)
            bf[ni] = *(const short8*)(&Bs[cur][(wn + ni * 16 + lm) * 32] + sw);
#pragma unroll
        for (int mi = 0; mi < 4; mi++)
#pragma unroll
            for (int ni = 0; ni < 4; ni++)
                acc[mi][ni] = __builtin_amdgcn_mfma_f32_16x16x32_bf16(
                    af[mi], bf[ni], acc[mi][ni], 0, 0, 0);
        __syncthreads();   // drains vmcnt (next tile landed) + guards buf reuse
    }

#pragma unroll
    for (int ni = 0; ni < 4; ni++) {
        const int n = n0 + wn + ni * 16 + lm;
        const float bv_ = bias[n];
        const int h = n >> 6, d = n & 63;
#pragma unroll
        for (int mi = 0; mi < 4; mi++)
#pragma unroll
            for (int r = 0; r < 4; r++) {
                const int m = m0 + wm + mi * 16 + quad * 4 + r;
                const int b = m >> 11, s = m & 2047;
                const u16 hv = f2bf((acc[mi][ni][r] + bv_) * oscale);
                if (which == 2)
                    out[(((size_t)(b * NH + h) * HD + d) * SEQ) + s] = hv;
                else
                    out[(((size_t)(b * NH + h) * SEQ + s) * HD) + d] = hv;
            }
    }
}

// ---------------- output projection (R10, unchanged) ----------------------
__launch_bounds__(256, 2)
__global__ void gemm_out(const u16* __restrict__ A, const u16* __restrict__ Wt,
                         const float* __restrict__ bias, float* __restrict__ out) {
    __shared__ u16 As[2][64 * 32];    // 2 x 4 KB
    __shared__ u16 Bs[2][128 * 32];   // 2 x 8 KB -> 24 KB total
    const int n0 = blockIdx.x * 128;
    const int m0 = blockIdx.y * 64;
    const int t = threadIdx.x;
    const int lane = t & 63, w = t >> 6, quad = lane >> 4, lm = lane & 15;
    const int wm = (w & 1) * 32, wn = (w >> 1) * 64;

    f32x4 acc[2][4] = {};

    auto stage = [&](int k0, int buf) {
        stage16(A, m0, k0, As[buf], w * 16, lane);
        stage16(Wt, n0, k0, Bs[buf], w * 32, lane);
        stage16(Wt, n0, k0, Bs[buf], w * 32 + 16, lane);
    };

    stage(0, 0);
    __syncthreads();
    for (int k0 = 0; k0 < 1024; k0 += 32) {
        const int cur = (k0 >> 5) & 1;
        if (k0 + 32 < 1024) stage(k0 + 32, cur ^ 1);
        short8 af[2], bf[4];
        const int sw = (quad ^ (lm & 3)) * 8;
#pragma unroll
        for (int mi = 0; mi < 2; mi++)
            af[mi] = *(const short8*)(&As[cur][(wm + mi * 16 + lm) * 32] + sw);
#pragma unroll
        for (int ni = 0; ni < 4; ni++)
            bf[ni] = *(const short8*)(&Bs[cur][(wn + ni * 16 + lm) * 32] + sw);
#pragma unroll
        for (int mi = 0; mi < 2; mi++)
#pragma unroll
            for (int ni = 0; ni < 4; ni++)
                acc[mi][ni] = __builtin_amdgcn_mfma_f32_16x16x32_bf16(
                    af[mi], bf[ni], acc[mi][ni], 0, 0, 0);
        __syncthreads();
    }

#pragma unroll
    for (int ni = 0; ni < 4; ni++) {
        const int n = n0 + wn + ni * 16 + lm;
        const float bv_ = bias[n];
#pragma unroll
        for (int mi = 0; mi < 2; mi++)
#pragma unroll
            for (int r = 0; r < 4; r++) {
                const int m = m0 + wm + mi * 16 + quad * 4 + r;
                out[(size_t)m * 1024 + n] = acc[mi][ni][r] + bv_;
            }
    }
}

// ---------------- flash attention, causal, BARRIER-FREE -------------------
// Grid 1024 blocks (longest-first), 256 thr = 4 independent waves; wave owns
// 16 q-rows. K/V frags load directly from global (L1/L2-hot, 16-line
// coalesced); LDS = per-wave P region only (8.7 KB). No __syncthreads.
__launch_bounds__(256, 4)
__global__ void attn_kernel(const u16* __restrict__ Q, const u16* __restrict__ K,
                            const u16* __restrict__ Vt, u16* __restrict__ Out) {
    constexpr int LDP = 68;           // 64 + 4 pad
    __shared__ u16 Ps[4 * 16 * LDP];  // 8704 B total LDS
    const int t = threadIdx.x;
    const int lane = t & 63, w = t >> 6, quad = lane >> 4, lm = lane & 15;
    const int qt = 31 - (blockIdx.x >> 5);   // longest-first
    const int bh = blockIdx.x & 31;
    const int b = bh >> 4, h = bh & 15;
    const size_t base = (size_t)(b * NH + h) * SEQ * HD;
    const u16* Qg = Q + base;
    const u16* Kg = K + base;
    const u16* Vg = Vt + base;
    const int q0 = qt * 64 + w * 16;
    const int nk = qt + 1;   // number of 64-key steps

    short8 qf[2];
#pragma unroll
    for (int kk = 0; kk < 2; kk++)
        qf[kk] = *(const short8*)(Qg + (size_t)(q0 + lm) * HD + kk * 32 + quad * 8);

    f32x4 oacc[4] = {};
    f32x4 lacc = {};
    short8 ones;
#pragma unroll
    for (int j = 0; j < 8; j++) ones[j] = (short)0x3F80;   // bf16 1.0

    u16* Pw = Ps + w * 16 * LDP;

    for (int kt = 0; kt < nk; kt++) {
        const u16* Kt = Kg + (size_t)(kt * 64) * HD;
        const u16* Vtp = Vg + kt * 64;

        // K frags straight from global: row n*16+lm (128B apart), 16B/lane.
        short8 kf0[4], kf1[4];
#pragma unroll
        for (int n = 0; n < 4; n++) {
            const u16* rowp = Kt + (size_t)(n * 16 + lm) * HD;
            kf0[n] = *(const short8*)(rowp + quad * 8);
            kf1[n] = *(const short8*)(rowp + 32 + quad * 8);
        }
        f32x4 sacc[4];
#pragma unroll
        for (int n = 0; n < 4; n++) {
            f32x4 a = {};
            a = __builtin_amdgcn_mfma_f32_16x16x32_bf16(qf[0], kf0[n], a, 0, 0, 0);
            a = __builtin_amdgcn_mfma_f32_16x16x32_bf16(qf[1], kf1[n], a, 0, 0, 0);
            sacc[n] = a;
        }
        if (kt == qt) {   // causal mask, diagonal tile only
#pragma unroll
            for (int n = 0; n < 4; n++)
#pragma unroll
                for (int r = 0; r < 4; r++)
                    if (n * 16 + lm > w * 16 + quad * 4 + r)
                        sacc[n][r] = -__builtin_inff();
        }
        // p = exp2(s) -> truncating bf16 -> per-wave LDS (no barrier needed)
#pragma unroll
        for (int n = 0; n < 4; n++)
#pragma unroll
            for (int r = 0; r < 4; r++)
                Pw[(quad * 4 + r) * LDP + n * 16 + lm] =
                    (u16)(__float_as_uint(exp2f(sacc[n][r])) >> 16);
        short8 pf[2];
#pragma unroll
        for (int k4 = 0; k4 < 2; k4++)
            pf[k4] = *(const short8*)(Pw + lm * LDP + k4 * 32 + quad * 8);
        // V frags straight from global: V^T row n*16+lm, key-chunk cols.
#pragma unroll
        for (int n = 0; n < 4; n++) {
            const u16* rowp = Vtp + (size_t)(n * 16 + lm) * SEQ;
#pragma unroll
            for (int k4 = 0; k4 < 2; k4++) {
                short8 vf = *(const short8*)(rowp + (k4 * 4 + quad) * 8);
                oacc[n] = __builtin_amdgcn_mfma_f32_16x16x32_bf16(pf[k4], vf, oacc[n], 0, 0, 0);
            }
        }
#pragma unroll
        for (int k4 = 0; k4 < 2; k4++)
            lacc = __builtin_amdgcn_mfma_f32_16x16x32_bf16(pf[k4], ones, lacc, 0, 0, 0);
    }

    // epilogue: every lane holds its rows' l in lacc[r]
    float inv[4];
#pragma unroll
    for (int r = 0; r < 4; r++) inv[r] = 1.0f / lacc[r];
#pragma unroll
    for (int n = 0; n < 4; n++)
#pragma unroll
        for (int r = 0; r < 4; r++) {
            const int qq = q0 + quad * 4 + r;
            Out[(size_t)(b * SEQ + qq) * HIDDEN + h * HD + n * 16 + lm] =
                f2bf(oacc[n][r] * inv[r]);
        }
}

// ---------------- launcher ------------------------------------------------
extern "C" void kernel_launch(void* const* d_in, const int* in_sizes, int n_in,
                              void* d_out, int out_size, void* d_ws, size_t ws_size,
                              hipStream_t stream) {
    const float* x  = (const float*)d_in[0];
    const float* Wq = (const float*)d_in[1];
    const float* bq = (const float*)d_in[2];
    const float* Wk = (const float*)d_in[3];
    const float* bk = (const float*)d_in[4];
    const float* Wv = (const float*)d_in[5];
    const float* bv = (const float*)d_in[6];
    const float* Wo = (const float*)d_in[7];
    const float* bo = (const float*)d_in[8];
    float* out = (float*)d_out;

    char* ws = (char*)d_ws;
    const size_t SZ_X = (size_t)4096 * 1024 * 2;   // 8 MB bf16
    const size_t SZ_W = (size_t)1024 * 1024 * 2;   // 2 MB bf16
    u16* xb    = (u16*)(ws);
    u16* wqb   = (u16*)(ws + SZ_X);
    u16* wkb   = (u16*)(ws + SZ_X + SZ_W);
    u16* wvb   = (u16*)(ws + SZ_X + 2 * SZ_W);
    u16* wob   = (u16*)(ws + SZ_X + 3 * SZ_W);
    u16* Qb    = (u16*)(ws + SZ_X + 4 * SZ_W);
    u16* Kb    = (u16*)(ws + 2 * SZ_X + 4 * SZ_W);
    u16* Vtb   = (u16*)(ws + 3 * SZ_X + 4 * SZ_W);
    u16* attnb = (u16*)(ws + 4 * SZ_X + 4 * SZ_W);

    cvt_all<<<4096, 256, 0, stream>>>(x, Wq, Wk, Wv, Wo, xb, wqb, wkb, wvb, wob);
    gemm_qkv<<<dim3(24, 32), 256, 0, stream>>>(xb, wqb, wkb, wvb, bq, bk, bv, Qb, Kb, Vtb);
    attn_kernel<<<BATCH * NH * (SEQ / 64), 256, 0, stream>>>(Qb, Kb, Vtb, attnb);
    gemm_out<<<dim3(8, 64), 256, 0, stream>>>(attnb, wob, bo, out);
}

// Round 12
// 217.725 us; speedup vs baseline: 1.3488x; 1.3488x over previous
//
#include <hip/hip_runtime.h>
#include <stdint.h>

// MultiHeadAttention: B=2, S=2048, HIDDEN=1024, NH=16, HD=64, causal.
// R12: revert R11's global-direct experiment (refuted: 57->149us, L2 latency
//      on the serial chain). Back to R8/R10 LDS staging, but Q-tile doubled
//      to 128 (wave = 32 q-rows): each staged K/V tile feeds 2x the MFMA ->
//      staging traffic, barriers, and steps all halve per unit work.
//      Grid 512, complementary pairing (i & i+256 sum to 17 steps), longest
//      first. LDS 49.4 KB. GEMMs/cvt byte-identical to R10.
// MFMA 16x16x32 bf16 layouts (HW-verified):
//   A/B frag: lane holds row[m=lane&15][k=(lane>>4)*8 + j]
//   C/D:      row=(lane>>4)*4+reg, col=lane&15

#define HIDDEN 1024
#define NH 16
#define HD 64
#define BATCH 2
#define SEQ 2048

typedef unsigned short u16;
typedef unsigned int u32;
typedef __attribute__((ext_vector_type(8))) short short8;   // 8 bf16
typedef __attribute__((ext_vector_type(4))) float f32x4;

typedef const __attribute__((address_space(1))) u32 gu32;
typedef __attribute__((address_space(3))) u32 lu32;

__device__ __forceinline__ u16 f2bf(float f) {
    u32 u = __float_as_uint(f);
    return (u16)((u + 0x7FFFu + ((u >> 16) & 1u)) >> 16);   // RNE
}

// ---------------- fused fp32 -> bf16 conversion (x + 4 weights) -----------
__global__ void cvt_all(const float* __restrict__ x, const float* __restrict__ Wq,
                        const float* __restrict__ Wk, const float* __restrict__ Wv,
                        const float* __restrict__ Wo, u16* __restrict__ xb,
                        u16* __restrict__ wqb, u16* __restrict__ wkb,
                        u16* __restrict__ wvb, u16* __restrict__ wob) {
    const int blk = blockIdx.x;
    const float* src; u16* dst; int base;
    if (blk < 2048)      { src = x;  dst = xb;  base = blk; }
    else if (blk < 2560) { src = Wq; dst = wqb; base = blk - 2048; }
    else if (blk < 3072) { src = Wk; dst = wkb; base = blk - 2560; }
    else if (blk < 3584) { src = Wv; dst = wvb; base = blk - 3072; }
    else                 { src = Wo; dst = wob; base = blk - 3584; }
    const int i = base * 256 + threadIdx.x;
    float4 a = ((const float4*)src)[2 * i];
    float4 b = ((const float4*)src)[2 * i + 1];
    union { u16 h[8]; uint4 v; } o;
    o.h[0] = f2bf(a.x); o.h[1] = f2bf(a.y); o.h[2] = f2bf(a.z); o.h[3] = f2bf(a.w);
    o.h[4] = f2bf(b.x); o.h[5] = f2bf(b.y); o.h[6] = f2bf(b.z); o.h[7] = f2bf(b.w);
    ((uint4*)dst)[i] = o.v;
}

// ---- async stage: 16 rows x 32 cols (64 B/row) per call, XOR-4 swizzle ----
__device__ __forceinline__ void stage16(const u16* __restrict__ G, int grow0,
                                        int k0, u16* lds, int rbase, int lane) {
    const int sr = lane >> 2;
    const int lc = (lane & 3) ^ (sr & 3);
    const u16* g = G + (size_t)(grow0 + rbase + sr) * 1024 + k0 + lc * 8;
    __builtin_amdgcn_global_load_lds((gu32*)g, (lu32*)(lds + rbase * 32), 16, 0, 0);
}

// ---------------- fused QKV projection (R10, unchanged) -------------------
__launch_bounds__(256, 3)
__global__ void gemm_qkv(const u16* __restrict__ A, const u16* __restrict__ Wqb,
                         const u16* __restrict__ Wkb, const u16* __restrict__ Wvb,
                         const float* __restrict__ bq, const float* __restrict__ bk,
                         const float* __restrict__ bv, u16* __restrict__ Qo,
                         u16* __restrict__ Ko, u16* __restrict__ Vo) {
    __shared__ u16 As[2][128 * 32];   // 2 x 8 KB
    __shared__ u16 Bs[2][128 * 32];   // 2 x 8 KB -> 32 KB total
    const int which = blockIdx.x >> 3;
    const int n0 = (blockIdx.x & 7) * 128;
    const int m0 = blockIdx.y * 128;
    const u16* Wt = (which == 0) ? Wqb : (which == 1) ? Wkb : Wvb;
    const float* bias = (which == 0) ? bq : (which == 1) ? bk : bv;
    u16* out = (which == 0) ? Qo : (which == 1) ? Ko : Vo;
    const float oscale = (which == 0) ? 0.18033688011112042f : 1.0f;  // log2e/8
    const int t = threadIdx.x;
    const int lane = t & 63, w = t >> 6, quad = lane >> 4, lm = lane & 15;
    const int wm = (w & 1) * 64, wn = (w >> 1) * 64;

    f32x4 acc[4][4] = {};

    auto stage = [&](int k0, int buf) {
        stage16(A, m0, k0, As[buf], w * 32, lane);
        stage16(A, m0, k0, As[buf], w * 32 + 16, lane);
        stage16(Wt, n0, k0, Bs[buf], w * 32, lane);
        stage16(Wt, n0, k0, Bs[buf], w * 32 + 16, lane);
    };

    stage(0, 0);
    __syncthreads();
    for (int k0 = 0; k0 < 1024; k0 += 32) {
        const int cur = (k0 >> 5) & 1;
        if (k0 + 32 < 1024) stage(k0 + 32, cur ^ 1);
        short8 af[4], bf[4];
        const int sw = (quad ^ (lm & 3)) * 8;   // swizzled slot offset (elems)
#pragma unroll
        for (int mi = 0; mi < 4; mi++)
            af[mi] = *(const short8*)(&As[cur][(wm + mi * 16 + lm) * 32] + sw);
#pragma unroll
        for (int ni = 0; ni < 4; ni++)
            bf[ni] = *(const short8*)(&Bs[cur][(wn + ni * 16 + lm) * 32] + sw);
#pragma unroll
        for (int mi = 0; mi < 4; mi++)
#pragma unroll
            for (int ni = 0; ni < 4; ni++)
                acc[mi][ni] = __builtin_amdgcn_mfma_f32_16x16x32_bf16(
                    af[mi], bf[ni], acc[mi][ni], 0, 0, 0);
        __syncthreads();   // drains vmcnt (next tile landed) + guards buf reuse
    }

#pragma unroll
    for (int ni = 0; ni < 4; ni++) {
        const int n = n0 + wn + ni * 16 + lm;
        const float bv_ = bias[n];
        const int h = n >> 6, d = n & 63;
#pragma unroll
        for (int mi = 0; mi < 4; mi++)
#pragma unroll
            for (int r = 0; r < 4; r++) {
                const int m = m0 + wm + mi * 16 + quad * 4 + r;
                const int b = m >> 11, s = m & 2047;
                const u16 hv = f2bf((acc[mi][ni][r] + bv_) * oscale);
                if (which == 2)
                    out[(((size_t)(b * NH + h) * HD + d) * SEQ) + s] = hv;
                else
                    out[(((size_t)(b * NH + h) * SEQ + s) * HD) + d] = hv;
            }
    }
}

// ---------------- output projection (R10, unchanged) ----------------------
__launch_bounds__(256, 2)
__global__ void gemm_out(const u16* __restrict__ A, const u16* __restrict__ Wt,
                         const float* __restrict__ bias, float* __restrict__ out) {
    __shared__ u16 As[2][64 * 32];    // 2 x 4 KB
    __shared__ u16 Bs[2][128 * 32];   // 2 x 8 KB -> 24 KB total
    const int n0 = blockIdx.x * 128;
    const int m0 = blockIdx.y * 64;
    const int t = threadIdx.x;
    const int lane = t & 63, w = t >> 6, quad = lane >> 4, lm = lane & 15;
    const int wm = (w & 1) * 32, wn = (w >> 1) * 64;

    f32x4 acc[2][4] = {};

    auto stage = [&](int k0, int buf) {
        stage16(A, m0, k0, As[buf], w * 16, lane);
        stage16(Wt, n0, k0, Bs[buf], w * 32, lane);
        stage16(Wt, n0, k0, Bs[buf], w * 32 + 16, lane);
    };

    stage(0, 0);
    __syncthreads();
    for (int k0 = 0; k0 < 1024; k0 += 32) {
        const int cur = (k0 >> 5) & 1;
        if (k0 + 32 < 1024) stage(k0 + 32, cur ^ 1);
        short8 af[2], bf[4];
        const int sw = (quad ^ (lm & 3)) * 8;
#pragma unroll
        for (int mi = 0; mi < 2; mi++)
            af[mi] = *(const short8*)(&As[cur][(wm + mi * 16 + lm) * 32] + sw);
#pragma unroll
        for (int ni = 0; ni < 4; ni++)
            bf[ni] = *(const short8*)(&Bs[cur][(wn + ni * 16 + lm) * 32] + sw);
#pragma unroll
        for (int mi = 0; mi < 2; mi++)
#pragma unroll
            for (int ni = 0; ni < 4; ni++)
                acc[mi][ni] = __builtin_amdgcn_mfma_f32_16x16x32_bf16(
                    af[mi], bf[ni], acc[mi][ni], 0, 0, 0);
        __syncthreads();
    }

#pragma unroll
    for (int ni = 0; ni < 4; ni++) {
        const int n = n0 + wn + ni * 16 + lm;
        const float bv_ = bias[n];
#pragma unroll
        for (int mi = 0; mi < 2; mi++)
#pragma unroll
            for (int r = 0; r < 4; r++) {
                const int m = m0 + wm + mi * 16 + quad * 4 + r;
                out[(size_t)m * 1024 + n] = acc[mi][ni][r] + bv_;
            }
    }
}

// ---------------- flash attention, causal, Q-tile 128 ---------------------
// Grid 512, 256 thr = 4 waves; wave owns 32 q-rows (2 m-frags); K-tile 64,
// R8 LDS staging (global_load_lds + XOR swizzle + dbuf, 1 barrier/step).
// Complementary pairing: blocks i, i+256 share pair&15 -> qt sum = 15.
__launch_bounds__(256, 3)
__global__ void attn_kernel(const u16* __restrict__ Q, const u16* __restrict__ K,
                            const u16* __restrict__ Vt, u16* __restrict__ Out) {
    constexpr int LDP = 68;           // 64 + 4 pad
    __shared__ u16 Ks[2][64 * 64];    // 2 x 8 KB, swizzled
    __shared__ u16 Vs[2][64 * 64];    // 2 x 8 KB, swizzled
    __shared__ u16 Ps[4 * 32 * LDP];  // 17408 B  -> total 50176 B
    const int t = threadIdx.x;
    const int lane = t & 63, w = t >> 6, quad = lane >> 4, lm = lane & 15;
    // complementary pairing + longest-first in the first half
    const int pair = blockIdx.x & 255;
    const int half = blockIdx.x >> 8;
    const int qt = half ? (pair & 15) : (15 - (pair & 15));   // Q-tile 0..15
    const int bh = (pair >> 4) | (half << 4);                  // 0..31
    const int b = bh >> 4, h = bh & 15;
    const size_t base = (size_t)(b * NH + h) * SEQ * HD;
    const u16* Qg = Q + base;
    const u16* Kg = K + base;
    const u16* Vg = Vt + base;
    const int q0 = qt * 128 + w * 32;
    const int nk = 2 * qt + 2;   // number of 64-key steps

    short8 qf[2][2];
#pragma unroll
    for (int m = 0; m < 2; m++)
#pragma unroll
        for (int kk = 0; kk < 2; kk++)
            qf[m][kk] = *(const short8*)(Qg + (size_t)(q0 + m * 16 + lm) * HD + kk * 32 + quad * 8);

    f32x4 oacc[2][4] = {};
    f32x4 lacc[2] = {};
    short8 ones;
#pragma unroll
    for (int j = 0; j < 8; j++) ones[j] = (short)0x3F80;   // bf16 1.0

    u16* Pw = Ps + w * 32 * LDP;

    const int srow = (lane >> 3);          // 0..7 within 8-row group
    const int schunk = (lane & 7) ^ srow;  // source logical chunk (r&7 == srow)
    auto stage_kv = [&](int kt, int buf) {
#pragma unroll
        for (int j = 0; j < 2; j++) {
            const int row = w * 16 + j * 8 + srow;
            const u16* gk = Kg + (size_t)(kt * 64 + row) * HD + schunk * 8;
            const u16* gv = Vg + (size_t)row * SEQ + kt * 64 + schunk * 8;
            __builtin_amdgcn_global_load_lds((gu32*)gk, (lu32*)(&Ks[buf][(w * 16 + j * 8) * 64]), 16, 0, 0);
            __builtin_amdgcn_global_load_lds((gu32*)gv, (lu32*)(&Vs[buf][(w * 16 + j * 8) * 64]), 16, 0, 0);
        }
    };

    auto compute_step = [&](const u16* Kc, const u16* Vc, int kt_) {
        f32x4 sacc[2][4];
#pragma unroll
        for (int n = 0; n < 4; n++) {
            const int r = n * 16 + lm;
            const u16* rowp = Kc + r * 64;
            short8 kf0 = *(const short8*)(rowp + ((quad ^ (r & 7)) * 8));
            short8 kf1 = *(const short8*)(rowp + (((quad + 4) ^ (r & 7)) * 8));
#pragma unroll
            for (int m = 0; m < 2; m++) {
                f32x4 a = {};
                a = __builtin_amdgcn_mfma_f32_16x16x32_bf16(qf[m][0], kf0, a, 0, 0, 0);
                a = __builtin_amdgcn_mfma_f32_16x16x32_bf16(qf[m][1], kf1, a, 0, 0, 0);
                sacc[m][n] = a;
            }
        }
        if (kt_ >= 2 * qt) {   // causal mask, diagonal region (last 2 steps)
            const int kb = kt_ * 64 - qt * 128 - w * 32;   // key rel - qrow base
#pragma unroll
            for (int m = 0; m < 2; m++)
#pragma unroll
                for (int n = 0; n < 4; n++)
#pragma unroll
                    for (int r = 0; r < 4; r++)
                        if (kb + n * 16 + lm > m * 16 + quad * 4 + r)
                            sacc[m][n][r] = -__builtin_inff();
        }
#pragma unroll
        for (int m = 0; m < 2; m++)
#pragma unroll
            for (int n = 0; n < 4; n++)
#pragma unroll
                for (int r = 0; r < 4; r++)
                    Pw[(m * 16 + quad * 4 + r) * LDP + n * 16 + lm] =
                        (u16)(__float_as_uint(exp2f(sacc[m][n][r])) >> 16);
        short8 pf[2][2];
#pragma unroll
        for (int m = 0; m < 2; m++)
#pragma unroll
            for (int k4 = 0; k4 < 2; k4++)
                pf[m][k4] = *(const short8*)(Pw + (m * 16 + lm) * LDP + k4 * 32 + quad * 8);
#pragma unroll
        for (int n = 0; n < 4; n++) {
            const int r = n * 16 + lm;
            const u16* rowp = Vc + r * 64;
#pragma unroll
            for (int k4 = 0; k4 < 2; k4++) {
                short8 vf = *(const short8*)(rowp + (((k4 * 4 + quad) ^ (r & 7)) * 8));
#pragma unroll
                for (int m = 0; m < 2; m++)
                    oacc[m][n] = __builtin_amdgcn_mfma_f32_16x16x32_bf16(pf[m][k4], vf, oacc[m][n], 0, 0, 0);
            }
        }
#pragma unroll
        for (int m = 0; m < 2; m++)
#pragma unroll
            for (int k4 = 0; k4 < 2; k4++)
                lacc[m] = __builtin_amdgcn_mfma_f32_16x16x32_bf16(pf[m][k4], ones, lacc[m], 0, 0, 0);
    };

    stage_kv(0, 0);
    __syncthreads();

    for (int kt = 0; kt < nk; kt++) {
        const int cur = kt & 1;
        if (kt + 1 < nk) stage_kv(kt + 1, cur ^ 1);   // async, no VGPRs held
        compute_step(Ks[cur], Vs[cur], kt);
        __syncthreads();   // drains vmcnt (tile kt+1 landed) + guards buf reuse
    }

    // epilogue: every lane holds its rows' l in lacc[m][r]
#pragma unroll
    for (int m = 0; m < 2; m++) {
        float inv[4];
#pragma unroll
        for (int r = 0; r < 4; r++) inv[r] = 1.0f / lacc[m][r];
#pragma unroll
        for (int n = 0; n < 4; n++)
#pragma unroll
            for (int r = 0; r < 4; r++) {
                const int qq = q0 + m * 16 + quad * 4 + r;
                Out[(size_t)(b * SEQ + qq) * HIDDEN + h * HD + n * 16 + lm] =
                    f2bf(oacc[m][n][r] * inv[r]);
            }
    }
}

// ---------------- launcher ------------------------------------------------
extern "C" void kernel_launch(void* const* d_in, const int* in_sizes, int n_in,
                              void* d_out, int out_size, void* d_ws, size_t ws_size,
                              hipStream_t stream) {
    const float* x  = (const float*)d_in[0];
    const float* Wq = (const float*)d_in[1];
    const float* bq = (const float*)d_in[2];
    const float* Wk = (const float*)d_in[3];
    const float* bk = (const float*)d_in[4];
    const float* Wv = (const float*)d_in[5];
    const float* bv = (const float*)d_in[6];
    const float* Wo = (const float*)d_in[7];
    const float* bo = (const float*)d_in[8];
    float* out = (float*)d_out;

    char* ws = (char*)d_ws;
    const size_t SZ_X = (size_t)4096 * 1024 * 2;   // 8 MB bf16
    const size_t SZ_W = (size_t)1024 * 1024 * 2;   // 2 MB bf16
    u16* xb    = (u16*)(ws);
    u16* wqb   = (u16*)(ws + SZ_X);
    u16* wkb   = (u16*)(ws + SZ_X + SZ_W);
    u16* wvb   = (u16*)(ws + SZ_X + 2 * SZ_W);
    u16* wob   = (u16*)(ws + SZ_X + 3 * SZ_W);
    u16* Qb    = (u16*)(ws + SZ_X + 4 * SZ_W);
    u16* Kb    = (u16*)(ws + 2 * SZ_X + 4 * SZ_W);
    u16* Vtb   = (u16*)(ws + 3 * SZ_X + 4 * SZ_W);
    u16* attnb = (u16*)(ws + 4 * SZ_X + 4 * SZ_W);

    cvt_all<<<4096, 256, 0, stream>>>(x, Wq, Wk, Wv, Wo, xb, wqb, wkb, wvb, wob);
    gemm_qkv<<<dim3(24, 32), 256, 0, stream>>>(xb, wqb, wkb, wvb, bq, bk, bv, Qb, Kb, Vtb);
    attn_kernel<<<BATCH * NH * (SEQ / 128), 256, 0, stream>>>(Qb, Kb, Vtb, attnb);
    gemm_out<<<dim3(8, 64), 256, 0, stream>>>(attnb, wob, bo, out);
}

// Round 13
// 200.076 us; speedup vs baseline: 1.4678x; 1.0882x over previous
//
#include <hip/hip_runtime.h>
#include <stdint.h>

// MultiHeadAttention: B=2, S=2048, HIDDEN=1024, NH=16, HD=64, causal.
// R13: (a) attn reverted to R10 exact (Q-tile 64; R12's Q-tile 128 refuted:
//      occupancy 13%, FETCH 4.5x). (b) gemm_qkv V-epilogue rewritten: the
//      [B,H,D,S] scatter put consecutive lanes 4KB apart (64 x 32B sectors
//      per store instr, ~16x write amplification) -- now each wave transposes
//      its 64x64 C-tile through freed As/Bs LDS (bf16, XOR-chunk swizzle) and
//      stores 8 coalesced 128-B lines. "rest" has been ~143us across ALL GEMM
//      structures -> shared V-scatter is the prime suspect.
// MFMA 16x16x32 bf16 layouts (HW-verified):
//   A/B frag: lane holds row[m=lane&15][k=(lane>>4)*8 + j]
//   C/D:      row=(lane>>4)*4+reg, col=lane&15

#define HIDDEN 1024
#define NH 16
#define HD 64
#define BATCH 2
#define SEQ 2048

typedef unsigned short u16;
typedef unsigned int u32;
typedef __attribute__((ext_vector_type(8))) short short8;   // 8 bf16
typedef __attribute__((ext_vector_type(4))) float f32x4;

typedef const __attribute__((address_space(1))) u32 gu32;
typedef __attribute__((address_space(3))) u32 lu32;

__device__ __forceinline__ u16 f2bf(float f) {
    u32 u = __float_as_uint(f);
    return (u16)((u + 0x7FFFu + ((u >> 16) & 1u)) >> 16);   // RNE
}

// ---------------- fused fp32 -> bf16 conversion (x + 4 weights) -----------
__global__ void cvt_all(const float* __restrict__ x, const float* __restrict__ Wq,
                        const float* __restrict__ Wk, const float* __restrict__ Wv,
                        const float* __restrict__ Wo, u16* __restrict__ xb,
                        u16* __restrict__ wqb, u16* __restrict__ wkb,
                        u16* __restrict__ wvb, u16* __restrict__ wob) {
    const int blk = blockIdx.x;
    const float* src; u16* dst; int base;
    if (blk < 2048)      { src = x;  dst = xb;  base = blk; }
    else if (blk < 2560) { src = Wq; dst = wqb; base = blk - 2048; }
    else if (blk < 3072) { src = Wk; dst = wkb; base = blk - 2560; }
    else if (blk < 3584) { src = Wv; dst = wvb; base = blk - 3072; }
    else                 { src = Wo; dst = wob; base = blk - 3584; }
    const int i = base * 256 + threadIdx.x;
    float4 a = ((const float4*)src)[2 * i];
    float4 b = ((const float4*)src)[2 * i + 1];
    union { u16 h[8]; uint4 v; } o;
    o.h[0] = f2bf(a.x); o.h[1] = f2bf(a.y); o.h[2] = f2bf(a.z); o.h[3] = f2bf(a.w);
    o.h[4] = f2bf(b.x); o.h[5] = f2bf(b.y); o.h[6] = f2bf(b.z); o.h[7] = f2bf(b.w);
    ((uint4*)dst)[i] = o.v;
}

// ---- async stage: 16 rows x 32 cols (64 B/row) per call, XOR-4 swizzle ----
__device__ __forceinline__ void stage16(const u16* __restrict__ G, int grow0,
                                        int k0, u16* lds, int rbase, int lane) {
    const int sr = lane >> 2;
    const int lc = (lane & 3) ^ (sr & 3);
    const u16* g = G + (size_t)(grow0 + rbase + sr) * 1024 + k0 + lc * 8;
    __builtin_amdgcn_global_load_lds((gu32*)g, (lu32*)(lds + rbase * 32), 16, 0, 0);
}

// ---------------- fused QKV projection ------------------------------------
// grid (24, 32). Q/K -> [B,H,S,D] direct; V -> [B,H,D,S] via LDS transpose.
__launch_bounds__(256, 3)
__global__ void gemm_qkv(const u16* __restrict__ A, const u16* __restrict__ Wqb,
                         const u16* __restrict__ Wkb, const u16* __restrict__ Wvb,
                         const float* __restrict__ bq, const float* __restrict__ bk,
                         const float* __restrict__ bv, u16* __restrict__ Qo,
                         u16* __restrict__ Ko, u16* __restrict__ Vo) {
    __shared__ u16 As[2][128 * 32];   // 2 x 8 KB
    __shared__ u16 Bs[2][128 * 32];   // 2 x 8 KB -> 32 KB total
    const int which = blockIdx.x >> 3;
    const int n0 = (blockIdx.x & 7) * 128;
    const int m0 = blockIdx.y * 128;
    const u16* Wt = (which == 0) ? Wqb : (which == 1) ? Wkb : Wvb;
    const float* bias = (which == 0) ? bq : (which == 1) ? bk : bv;
    u16* out = (which == 0) ? Qo : (which == 1) ? Ko : Vo;
    const float oscale = (which == 0) ? 0.18033688011112042f : 1.0f;  // log2e/8
    const int t = threadIdx.x;
    const int lane = t & 63, w = t >> 6, quad = lane >> 4, lm = lane & 15;
    const int wm = (w & 1) * 64, wn = (w >> 1) * 64;

    f32x4 acc[4][4] = {};

    auto stage = [&](int k0, int buf) {
        stage16(A, m0, k0, As[buf], w * 32, lane);
        stage16(A, m0, k0, As[buf], w * 32 + 16, lane);
        stage16(Wt, n0, k0, Bs[buf], w * 32, lane);
        stage16(Wt, n0, k0, Bs[buf], w * 32 + 16, lane);
    };

    stage(0, 0);
    __syncthreads();
    for (int k0 = 0; k0 < 1024; k0 += 32) {
        const int cur = (k0 >> 5) & 1;
        if (k0 + 32 < 1024) stage(k0 + 32, cur ^ 1);
        short8 af[4], bf[4];
        const int sw = (quad ^ (lm & 3)) * 8;   // swizzled slot offset (elems)
#pragma unroll
        for (int mi = 0; mi < 4; mi++)
            af[mi] = *(const short8*)(&As[cur][(wm + mi * 16 + lm) * 32] + sw);
#pragma unroll
        for (int ni = 0; ni < 4; ni++)
            bf[ni] = *(const short8*)(&Bs[cur][(wn + ni * 16 + lm) * 32] + sw);
#pragma unroll
        for (int mi = 0; mi < 4; mi++)
#pragma unroll
            for (int ni = 0; ni < 4; ni++)
                acc[mi][ni] = __builtin_amdgcn_mfma_f32_16x16x32_bf16(
                    af[mi], bf[ni], acc[mi][ni], 0, 0, 0);
        __syncthreads();   // drains vmcnt (next tile landed) + guards buf reuse
    }

    if (which == 2) {
        // V: per-wave LDS transpose -> coalesced [B,H,D,S] stores.
        // Element (n_loc, m_loc) -> Tw[n_loc*64 + ((m_loc>>3)^(n_loc&7))*8 + (m_loc&7)]
        u16* Tw = ((w < 2) ? (u16*)As : (u16*)Bs) + (w & 1) * 4096;
#pragma unroll
        for (int ni = 0; ni < 4; ni++) {
            const int n_loc = ni * 16 + lm;
            const float bv_ = bias[n0 + wn + n_loc];
#pragma unroll
            for (int mi = 0; mi < 4; mi++)
#pragma unroll
                for (int r = 0; r < 4; r++) {
                    const int m_loc = mi * 16 + quad * 4 + r;
                    Tw[n_loc * 64 + (((m_loc >> 3) ^ (n_loc & 7)) * 8) + (m_loc & 7)] =
                        f2bf(acc[mi][ni][r] + bv_);
                }
        }
        // same-wave region: compiler orders LDS write->read via lgkmcnt
        const int hh = (n0 + wn) >> 6;
        const int mg = m0 + wm;             // 64-aligned, never straddles batch
        const int bb = mg >> 11, s0 = mg & 2047;
        u16* outp = out + ((size_t)(bb * NH + hh) * HD) * SEQ;
        const int cm = lane & 7;            // logical m-chunk (8 elems)
#pragma unroll
        for (int i = 0; i < 8; i++) {
            const int n_loc = i * 8 + (lane >> 3);   // d
            short8 v = *(const short8*)(Tw + n_loc * 64 + ((cm ^ (n_loc & 7)) * 8));
            *(short8*)(outp + (size_t)n_loc * SEQ + s0 + cm * 8) = v;
        }
    } else {
#pragma unroll
        for (int ni = 0; ni < 4; ni++) {
            const int n = n0 + wn + ni * 16 + lm;
            const float bv_ = bias[n];
            const int h = n >> 6, d = n & 63;
#pragma unroll
            for (int mi = 0; mi < 4; mi++)
#pragma unroll
                for (int r = 0; r < 4; r++) {
                    const int m = m0 + wm + mi * 16 + quad * 4 + r;
                    const int b = m >> 11, s = m & 2047;
                    out[(((size_t)(b * NH + h) * SEQ + s) * HD) + d] =
                        f2bf((acc[mi][ni][r] + bv_) * oscale);
                }
        }
    }
}

// ---------------- output projection (R10, unchanged) ----------------------
__launch_bounds__(256, 2)
__global__ void gemm_out(const u16* __restrict__ A, const u16* __restrict__ Wt,
                         const float* __restrict__ bias, float* __restrict__ out) {
    __shared__ u16 As[2][64 * 32];    // 2 x 4 KB
    __shared__ u16 Bs[2][128 * 32];   // 2 x 8 KB -> 24 KB total
    const int n0 = blockIdx.x * 128;
    const int m0 = blockIdx.y * 64;
    const int t = threadIdx.x;
    const int lane = t & 63, w = t >> 6, quad = lane >> 4, lm = lane & 15;
    const int wm = (w & 1) * 32, wn = (w >> 1) * 64;

    f32x4 acc[2][4] = {};

    auto stage = [&](int k0, int buf) {
        stage16(A, m0, k0, As[buf], w * 16, lane);
        stage16(Wt, n0, k0, Bs[buf], w * 32, lane);
        stage16(Wt, n0, k0, Bs[buf], w * 32 + 16, lane);
    };

    stage(0, 0);
    __syncthreads();
    for (int k0 = 0; k0 < 1024; k0 += 32) {
        const int cur = (k0 >> 5) & 1;
        if (k0 + 32 < 1024) stage(k0 + 32, cur ^ 1);
        short8 af[2], bf[4];
        const int sw = (quad ^ (lm & 3)) * 8;
#pragma unroll
        for (int mi = 0; mi < 2; mi++)
            af[mi] = *(const short8*)(&As[cur][(wm + mi * 16 + lm) * 32] + sw);
#pragma unroll
        for (int ni = 0; ni < 4; ni++)
            bf[ni] = *(const short8*)(&Bs[cur][(wn + ni * 16 + lm) * 32] + sw);
#pragma unroll
        for (int mi = 0; mi < 2; mi++)
#pragma unroll
            for (int ni = 0; ni < 4; ni++)
                acc[mi][ni] = __builtin_amdgcn_mfma_f32_16x16x32_bf16(
                    af[mi], bf[ni], acc[mi][ni], 0, 0, 0);
        __syncthreads();
    }

#pragma unroll
    for (int ni = 0; ni < 4; ni++) {
        const int n = n0 + wn + ni * 16 + lm;
        const float bv_ = bias[n];
#pragma unroll
        for (int mi = 0; mi < 2; mi++)
#pragma unroll
            for (int r = 0; r < 4; r++) {
                const int m = m0 + wm + mi * 16 + quad * 4 + r;
                out[(size_t)m * 1024 + n] = acc[mi][ni][r] + bv_;
            }
    }
}

// ---------------- flash attention, causal (R10 exact) ---------------------
// Grid 1024 blocks (longest-first), 256 thr = 4 waves; wave owns 16 q-rows;
// Q-tile 64, K-tile 64, double-buffered LDS via global_load_lds, XOR swizzle.
__launch_bounds__(256, 3)
__global__ void attn_kernel(const u16* __restrict__ Q, const u16* __restrict__ K,
                            const u16* __restrict__ Vt, u16* __restrict__ Out) {
    constexpr int LDP = 68;           // Ps keeps padded layout (VALU-written)
    __shared__ u16 Ks[2][64 * 64];    // 2 x 8 KB, swizzled
    __shared__ u16 Vs[2][64 * 64];    // 2 x 8 KB, swizzled
    __shared__ u16 Ps[4 * 16 * LDP];  // 8704 B   -> total 41472 B
    const int t = threadIdx.x;
    const int lane = t & 63, w = t >> 6, quad = lane >> 4, lm = lane & 15;
    const int qt = 31 - (blockIdx.x >> 5);   // longest-first
    const int bh = blockIdx.x & 31;
    const int b = bh >> 4, h = bh & 15;
    const size_t base = (size_t)(b * NH + h) * SEQ * HD;
    const u16* Qg = Q + base;
    const u16* Kg = K + base;
    const u16* Vg = Vt + base;
    const int q0 = qt * 64 + w * 16;
    const int nk = qt + 1;   // number of 64-key steps

    short8 qf[2];
#pragma unroll
    for (int kk = 0; kk < 2; kk++)
        qf[kk] = *(const short8*)(Qg + (size_t)(q0 + lm) * HD + kk * 32 + quad * 8);

    f32x4 oacc[4] = {};
    f32x4 lacc = {};
    short8 ones;
#pragma unroll
    for (int j = 0; j < 8; j++) ones[j] = (short)0x3F80;   // bf16 1.0

    u16* Pw = Ps + w * 16 * LDP;

    const int srow = (lane >> 3);          // 0..7 within 8-row group
    const int schunk = (lane & 7) ^ srow;  // source logical chunk (r&7 == srow)
    auto stage_kv = [&](int kt, int buf) {
#pragma unroll
        for (int j = 0; j < 2; j++) {
            const int row = w * 16 + j * 8 + srow;
            const u16* gk = Kg + (size_t)(kt * 64 + row) * HD + schunk * 8;
            const u16* gv = Vg + (size_t)row * SEQ + kt * 64 + schunk * 8;
            __builtin_amdgcn_global_load_lds((gu32*)gk, (lu32*)(&Ks[buf][(w * 16 + j * 8) * 64]), 16, 0, 0);
            __builtin_amdgcn_global_load_lds((gu32*)gv, (lu32*)(&Vs[buf][(w * 16 + j * 8) * 64]), 16, 0, 0);
        }
    };

    auto compute_step = [&](const u16* Kc, const u16* Vc, int kt_) {
        f32x4 sacc[4];
#pragma unroll
        for (int n = 0; n < 4; n++) {
            const int r = n * 16 + lm;
            const u16* rowp = Kc + r * 64;
            short8 kf0 = *(const short8*)(rowp + ((quad ^ (r & 7)) * 8));
            short8 kf1 = *(const short8*)(rowp + (((quad + 4) ^ (r & 7)) * 8));
            f32x4 a = {};
            a = __builtin_amdgcn_mfma_f32_16x16x32_bf16(qf[0], kf0, a, 0, 0, 0);
            a = __builtin_amdgcn_mfma_f32_16x16x32_bf16(qf[1], kf1, a, 0, 0, 0);
            sacc[n] = a;
        }
        if (kt_ == qt) {   // causal mask, diagonal tile only
#pragma unroll
            for (int n = 0; n < 4; n++)
#pragma unroll
                for (int r = 0; r < 4; r++)
                    if (n * 16 + lm > w * 16 + quad * 4 + r)
                        sacc[n][r] = -__builtin_inff();
        }
#pragma unroll
        for (int n = 0; n < 4; n++)
#pragma unroll
            for (int r = 0; r < 4; r++)
                Pw[(quad * 4 + r) * LDP + n * 16 + lm] =
                    (u16)(__float_as_uint(exp2f(sacc[n][r])) >> 16);
        short8 pf[2];
#pragma unroll
        for (int k4 = 0; k4 < 2; k4++)
            pf[k4] = *(const short8*)(Pw + lm * LDP + k4 * 32 + quad * 8);
#pragma unroll
        for (int n = 0; n < 4; n++) {
            const int r = n * 16 + lm;
            const u16* rowp = Vc + r * 64;
#pragma unroll
            for (int k4 = 0; k4 < 2; k4++) {
                short8 vf = *(const short8*)(rowp + (((k4 * 4 + quad) ^ (r & 7)) * 8));
                oacc[n] = __builtin_amdgcn_mfma_f32_16x16x32_bf16(pf[k4], vf, oacc[n], 0, 0, 0);
            }
        }
#pragma unroll
        for (int k4 = 0; k4 < 2; k4++)
            lacc = __builtin_amdgcn_mfma_f32_16x16x32_bf16(pf[k4], ones, lacc, 0, 0, 0);
    };

    stage_kv(0, 0);
    __syncthreads();

    for (int kt = 0; kt < nk; kt++) {
        const int cur = kt & 1;
        if (kt + 1 < nk) stage_kv(kt + 1, cur ^ 1);   // async, no VGPRs held
        compute_step(Ks[cur], Vs[cur], kt);
        __syncthreads();   // drains vmcnt (tile kt+1 landed) + guards buf reuse
    }

    float inv[4];
#pragma unroll
    for (int r = 0; r < 4; r++) inv[r] = 1.0f / lacc[r];
#pragma unroll
    for (int n = 0; n < 4; n++)
#pragma unroll
        for (int r = 0; r < 4; r++) {
            const int qq = q0 + quad * 4 + r;
            Out[(size_t)(b * SEQ + qq) * HIDDEN + h * HD + n * 16 + lm] =
                f2bf(oacc[n][r] * inv[r]);
        }
}

// ---------------- launcher ------------------------------------------------
extern "C" void kernel_launch(void* const* d_in, const int* in_sizes, int n_in,
                              void* d_out, int out_size, void* d_ws, size_t ws_size,
                              hipStream_t stream) {
    const float* x  = (const float*)d_in[0];
    const float* Wq = (const float*)d_in[1];
    const float* bq = (const float*)d_in[2];
    const float* Wk = (const float*)d_in[3];
    const float* bk = (const float*)d_in[4];
    const float* Wv = (const float*)d_in[5];
    const float* bv = (const float*)d_in[6];
    const float* Wo = (const float*)d_in[7];
    const float* bo = (const float*)d_in[8];
    float* out = (float*)d_out;

    char* ws = (char*)d_ws;
    const size_t SZ_X = (size_t)4096 * 1024 * 2;   // 8 MB bf16
    const size_t SZ_W = (size_t)1024 * 1024 * 2;   // 2 MB bf16
    u16* xb    = (u16*)(ws);
    u16* wqb   = (u16*)(ws + SZ_X);
    u16* wkb   = (u16*)(ws + SZ_X + SZ_W);
    u16* wvb   = (u16*)(ws + SZ_X + 2 * SZ_W);
    u16* wob   = (u16*)(ws + SZ_X + 3 * SZ_W);
    u16* Qb    = (u16*)(ws + SZ_X + 4 * SZ_W);
    u16* Kb    = (u16*)(ws + 2 * SZ_X + 4 * SZ_W);
    u16* Vtb   = (u16*)(ws + 3 * SZ_X + 4 * SZ_W);
    u16* attnb = (u16*)(ws + 4 * SZ_X + 4 * SZ_W);

    cvt_all<<<4096, 256, 0, stream>>>(x, Wq, Wk, Wv, Wo, xb, wqb, wkb, wvb, wob);
    gemm_qkv<<<dim3(24, 32), 256, 0, stream>>>(xb, wqb, wkb, wvb, bq, bk, bv, Qb, Kb, Vtb);
    attn_kernel<<<BATCH * NH * (SEQ / 64), 256, 0, stream>>>(Qb, Kb, Vtb, attnb);
    gemm_out<<<dim3(8, 64), 256, 0, stream>>>(attnb, wob, bo, out);
}